// Round 1
// baseline (510.434 us; speedup 1.0000x reference)
//
#include <hip/hip_runtime.h>
#include <math.h>

// CentroidInstanceLoss: N=2M points, D=16, B=8 subbatches, M=32 labels.
// out = (L_pull + L_push)/B  (single fp32 scalar)

#define DD 16
#define MM 32
#define BBATCH 8
#define SEGS 256          // B*M
#define DELTA_V 0.5f
#define DELTA_D 1.5f
#define NEPS 1e-8f

#define NBLK 512
#define NTHR 256

// ws layout (floats):
//   [0,4096)      seg_sum   [seg][d]
//   [4096,4352)   seg_cnt   [seg]
//   [4352,8448)   mus       [seg][d]
//   [8448,8704)   invw      [seg]   = 1/(M*count)
//   [8704]        pull_acc
//   [8705]        push_acc
#define WS_FLOATS 8706

__device__ __forceinline__ float block_reduce_sum(float v) {
    #pragma unroll
    for (int o = 32; o > 0; o >>= 1) v += __shfl_down(v, o, 64);
    __shared__ float red[4];
    int wid  = threadIdx.x >> 6;
    int lane = threadIdx.x & 63;
    if (lane == 0) red[wid] = v;
    __syncthreads();
    v = (threadIdx.x < (blockDim.x >> 6)) ? red[threadIdx.x] : 0.0f;
    if (wid == 0) {
        #pragma unroll
        for (int o = 32; o > 0; o >>= 1) v += __shfl_down(v, o, 64);
    }
    return v;  // valid on thread 0
}

__global__ void k_segsum(const float4* __restrict__ o4,
                         const int* __restrict__ labels,
                         const int* __restrict__ sub,
                         float* __restrict__ seg_sum,
                         float* __restrict__ seg_cnt,
                         int n) {
    // transposed LDS accumulators: lsT[d][seg] -> consecutive lanes (consecutive
    // segs) hit distinct banks; lanes i,i+32 share seg (2-way, free)
    __shared__ float lsT[DD * SEGS];
    __shared__ float lcnt[SEGS];
    for (int i = threadIdx.x; i < DD * SEGS; i += blockDim.x) lsT[i] = 0.0f;
    for (int i = threadIdx.x; i < SEGS; i += blockDim.x) lcnt[i] = 0.0f;
    __syncthreads();

    const int stride = gridDim.x * blockDim.x;
    for (int p = blockIdx.x * blockDim.x + threadIdx.x; p < n; p += stride) {
        float4 a = o4[4 * p + 0];
        float4 b = o4[4 * p + 1];
        float4 c = o4[4 * p + 2];
        float4 e = o4[4 * p + 3];
        float ss = a.x*a.x + a.y*a.y + a.z*a.z + a.w*a.w
                 + b.x*b.x + b.y*b.y + b.z*b.z + b.w*b.w
                 + c.x*c.x + c.y*c.y + c.z*c.z + c.w*c.w
                 + e.x*e.x + e.y*e.y + e.z*e.z + e.w*e.w;
        float rn = 1.0f / (sqrtf(ss) + NEPS);
        int seg = sub[p] * MM + labels[p];
        atomicAdd(&lsT[ 0*SEGS + seg], a.x * rn);
        atomicAdd(&lsT[ 1*SEGS + seg], a.y * rn);
        atomicAdd(&lsT[ 2*SEGS + seg], a.z * rn);
        atomicAdd(&lsT[ 3*SEGS + seg], a.w * rn);
        atomicAdd(&lsT[ 4*SEGS + seg], b.x * rn);
        atomicAdd(&lsT[ 5*SEGS + seg], b.y * rn);
        atomicAdd(&lsT[ 6*SEGS + seg], b.z * rn);
        atomicAdd(&lsT[ 7*SEGS + seg], b.w * rn);
        atomicAdd(&lsT[ 8*SEGS + seg], c.x * rn);
        atomicAdd(&lsT[ 9*SEGS + seg], c.y * rn);
        atomicAdd(&lsT[10*SEGS + seg], c.z * rn);
        atomicAdd(&lsT[11*SEGS + seg], c.w * rn);
        atomicAdd(&lsT[12*SEGS + seg], e.x * rn);
        atomicAdd(&lsT[13*SEGS + seg], e.y * rn);
        atomicAdd(&lsT[14*SEGS + seg], e.z * rn);
        atomicAdd(&lsT[15*SEGS + seg], e.w * rn);
        atomicAdd(&lcnt[seg], 1.0f);
    }
    __syncthreads();
    for (int s = threadIdx.x; s < SEGS; s += blockDim.x) {
        #pragma unroll
        for (int d = 0; d < DD; ++d)
            atomicAdd(&seg_sum[s * DD + d], lsT[d * SEGS + s]);
        atomicAdd(&seg_cnt[s], lcnt[s]);
    }
}

__global__ void k_finalize_push(float* __restrict__ ws) {
    const float* seg_sum = ws;
    const float* seg_cnt = ws + 4096;
    float* mus  = ws + 4352;
    float* invw = ws + 8448;
    float* accs = ws + 8704;

    __shared__ float muT[DD * SEGS];
    int t = threadIdx.x;  // 256 threads == one per segment
    float cnt = seg_cnt[t];
    float ic  = (cnt > 0.0f) ? 1.0f / cnt : 0.0f;
    #pragma unroll
    for (int d = 0; d < DD; ++d) {
        float m = seg_sum[t * DD + d] * ic;
        mus[t * DD + d]  = m;
        muT[d * SEGS + t] = m;
    }
    invw[t] = (cnt > 0.0f) ? 1.0f / ((float)MM * cnt) : 0.0f;
    __syncthreads();

    int b = t >> 5, m1 = t & 31;
    float acc = 0.0f;
    for (int m2 = 0; m2 < MM; ++m2) {
        float pd = 0.0f;
        #pragma unroll
        for (int d = 0; d < DD; ++d)
            pd += fabsf(muT[d * SEGS + b * MM + m1] - muT[d * SEGS + b * MM + m2]);
        float h = 2.0f * DELTA_D - pd;
        if (m2 != m1 && h > 0.0f) acc += h * h;
    }
    float tot = block_reduce_sum(acc);
    if (t == 0) accs[1] = tot / (float)(MM * (MM - 1));
}

__global__ void k_pull(const float4* __restrict__ o4,
                       const int* __restrict__ labels,
                       const int* __restrict__ sub,
                       const float* __restrict__ mus,
                       const float* __restrict__ invw,
                       float* __restrict__ pull_acc,
                       int n) {
    __shared__ float muT[DD * SEGS];  // transposed: conflict-free per-d reads
    __shared__ float siw[SEGS];
    for (int i = threadIdx.x; i < DD * SEGS; i += blockDim.x) {
        int s = i & (SEGS - 1);
        int d = i >> 8;
        muT[d * SEGS + s] = mus[s * DD + d];
    }
    for (int i = threadIdx.x; i < SEGS; i += blockDim.x) siw[i] = invw[i];
    __syncthreads();

    float acc = 0.0f;
    const int stride = gridDim.x * blockDim.x;
    for (int p = blockIdx.x * blockDim.x + threadIdx.x; p < n; p += stride) {
        float4 a = o4[4 * p + 0];
        float4 b = o4[4 * p + 1];
        float4 c = o4[4 * p + 2];
        float4 e = o4[4 * p + 3];
        float ss = a.x*a.x + a.y*a.y + a.z*a.z + a.w*a.w
                 + b.x*b.x + b.y*b.y + b.z*b.z + b.w*b.w
                 + c.x*c.x + c.y*c.y + c.z*c.z + c.w*c.w
                 + e.x*e.x + e.y*e.y + e.z*e.z + e.w*e.w;
        float rn = 1.0f / (sqrtf(ss) + NEPS);
        int seg = sub[p] * MM + labels[p];
        float dist;
        dist  = fabsf(muT[ 0*SEGS + seg] - a.x * rn);
        dist += fabsf(muT[ 1*SEGS + seg] - a.y * rn);
        dist += fabsf(muT[ 2*SEGS + seg] - a.z * rn);
        dist += fabsf(muT[ 3*SEGS + seg] - a.w * rn);
        dist += fabsf(muT[ 4*SEGS + seg] - b.x * rn);
        dist += fabsf(muT[ 5*SEGS + seg] - b.y * rn);
        dist += fabsf(muT[ 6*SEGS + seg] - b.z * rn);
        dist += fabsf(muT[ 7*SEGS + seg] - b.w * rn);
        dist += fabsf(muT[ 8*SEGS + seg] - c.x * rn);
        dist += fabsf(muT[ 9*SEGS + seg] - c.y * rn);
        dist += fabsf(muT[10*SEGS + seg] - c.z * rn);
        dist += fabsf(muT[11*SEGS + seg] - c.w * rn);
        dist += fabsf(muT[12*SEGS + seg] - e.x * rn);
        dist += fabsf(muT[13*SEGS + seg] - e.y * rn);
        dist += fabsf(muT[14*SEGS + seg] - e.z * rn);
        dist += fabsf(muT[15*SEGS + seg] - e.w * rn);
        float h = dist - DELTA_V;
        if (h > 0.0f) acc = fmaf(h * h, siw[seg], acc);
    }
    float tot = block_reduce_sum(acc);
    if (threadIdx.x == 0) atomicAdd(pull_acc, tot);
}

__global__ void k_final(const float* __restrict__ accs, float* __restrict__ out) {
    out[0] = (accs[0] + accs[1]) * (1.0f / (float)BBATCH);
}

extern "C" void kernel_launch(void* const* d_in, const int* in_sizes, int n_in,
                              void* d_out, int out_size, void* d_ws, size_t ws_size,
                              hipStream_t stream) {
    const float* outputs = (const float*)d_in[0];
    const int* labels    = (const int*)d_in[1];
    const int* sub       = (const int*)d_in[2];
    int n = in_sizes[0] / DD;

    float* ws       = (float*)d_ws;
    float* seg_sum  = ws;
    float* seg_cnt  = ws + 4096;
    float* mus      = ws + 4352;
    float* invw     = ws + 8448;
    float* accs     = ws + 8704;

    hipMemsetAsync(d_ws, 0, WS_FLOATS * sizeof(float), stream);

    k_segsum<<<NBLK, NTHR, 0, stream>>>((const float4*)outputs, labels, sub,
                                        seg_sum, seg_cnt, n);
    k_finalize_push<<<1, NTHR, 0, stream>>>(ws);
    k_pull<<<NBLK, NTHR, 0, stream>>>((const float4*)outputs, labels, sub,
                                      mus, invw, accs + 0, n);
    k_final<<<1, 1, 0, stream>>>(accs, (float*)d_out);
}

// Round 2
// 509.174 us; speedup vs baseline: 1.0025x; 1.0025x over previous
//
#include <hip/hip_runtime.h>
#include <math.h>

// CentroidInstanceLoss: N=2M points, D=16, B=8 subbatches, M=32 labels.
// out = (L_pull + L_push)/B  (single fp32 scalar)

#define DD 16
#define MM 32
#define BBATCH 8
#define SEGS 256          // B*M
#define DELTA_V 0.5f
#define DELTA_D 1.5f
#define NEPS 1e-8f

#define NBLK 512
#define NTHR 256

// ws layout (floats):
//   [0,4096)      seg_sum   [seg][d]    (atomically accumulated, HW fp atomics)
//   [4096,4352)   seg_cnt   [seg]
//   [4352,8448)   mus       [seg][d]
//   [8448,8704)   invw      [seg]   = 1/(M*count)
//   [8704]        push_acc
//   [8705,9217)   pull_part [NBLK]  per-block pull partials (no atomics)
#define WS_ZERO_FLOATS 4352

__device__ __forceinline__ float lds_fadd(float* p, float v) {
    return __hip_atomic_fetch_add(p, v, __ATOMIC_RELAXED, __HIP_MEMORY_SCOPE_WORKGROUP);
}

__device__ __forceinline__ float block_reduce_sum(float v) {
    #pragma unroll
    for (int o = 32; o > 0; o >>= 1) v += __shfl_down(v, o, 64);
    __shared__ float red[4];
    int wid  = threadIdx.x >> 6;
    int lane = threadIdx.x & 63;
    if (lane == 0) red[wid] = v;
    __syncthreads();
    v = (threadIdx.x < (blockDim.x >> 6)) ? red[threadIdx.x] : 0.0f;
    if (wid == 0) {
        #pragma unroll
        for (int o = 32; o > 0; o >>= 1) v += __shfl_down(v, o, 64);
    }
    return v;  // valid on thread 0
}

__global__ void __launch_bounds__(NTHR, 4)
k_segsum(const float4* __restrict__ o4,
         const int* __restrict__ labels,
         const int* __restrict__ sub,
         float* __restrict__ seg_sum,
         float* __restrict__ seg_cnt,
         int n) {
    // transposed LDS accumulators: lsT[d][seg] -> consecutive lanes (consecutive
    // segs) hit distinct banks; lanes i,i+32 share seg (2-way, cheap)
    __shared__ float lsT[DD * SEGS];
    __shared__ float lcnt[SEGS];
    for (int i = threadIdx.x; i < DD * SEGS; i += NTHR) lsT[i] = 0.0f;
    for (int i = threadIdx.x; i < SEGS; i += NTHR) lcnt[i] = 0.0f;
    __syncthreads();

    const int stride = gridDim.x * NTHR;
    #pragma unroll 2
    for (int p = blockIdx.x * NTHR + threadIdx.x; p < n; p += stride) {
        int lb = labels[p];
        int sb = sub[p];
        float4 a = o4[4 * p + 0];
        float4 b = o4[4 * p + 1];
        float4 c = o4[4 * p + 2];
        float4 e = o4[4 * p + 3];
        float ss = a.x*a.x + a.y*a.y + a.z*a.z + a.w*a.w
                 + b.x*b.x + b.y*b.y + b.z*b.z + b.w*b.w
                 + c.x*c.x + c.y*c.y + c.z*c.z + c.w*c.w
                 + e.x*e.x + e.y*e.y + e.z*e.z + e.w*e.w;
        float rn = 1.0f / (sqrtf(ss) + NEPS);
        int seg = sb * MM + lb;
        lds_fadd(&lsT[ 0*SEGS + seg], a.x * rn);
        lds_fadd(&lsT[ 1*SEGS + seg], a.y * rn);
        lds_fadd(&lsT[ 2*SEGS + seg], a.z * rn);
        lds_fadd(&lsT[ 3*SEGS + seg], a.w * rn);
        lds_fadd(&lsT[ 4*SEGS + seg], b.x * rn);
        lds_fadd(&lsT[ 5*SEGS + seg], b.y * rn);
        lds_fadd(&lsT[ 6*SEGS + seg], b.z * rn);
        lds_fadd(&lsT[ 7*SEGS + seg], b.w * rn);
        lds_fadd(&lsT[ 8*SEGS + seg], c.x * rn);
        lds_fadd(&lsT[ 9*SEGS + seg], c.y * rn);
        lds_fadd(&lsT[10*SEGS + seg], c.z * rn);
        lds_fadd(&lsT[11*SEGS + seg], c.w * rn);
        lds_fadd(&lsT[12*SEGS + seg], e.x * rn);
        lds_fadd(&lsT[13*SEGS + seg], e.y * rn);
        lds_fadd(&lsT[14*SEGS + seg], e.z * rn);
        lds_fadd(&lsT[15*SEGS + seg], e.w * rn);
        lds_fadd(&lcnt[seg], 1.0f);
    }
    __syncthreads();
    // flush: hardware fp32 global atomics (global_atomic_add_f32, no CAS loop)
    for (int s = threadIdx.x; s < SEGS; s += NTHR) {
        #pragma unroll
        for (int d = 0; d < DD; ++d)
            unsafeAtomicAdd(&seg_sum[s * DD + d], lsT[d * SEGS + s]);
        unsafeAtomicAdd(&seg_cnt[s], lcnt[s]);
    }
}

__global__ void k_finalize_push(float* __restrict__ ws) {
    const float* seg_sum = ws;
    const float* seg_cnt = ws + 4096;
    float* mus  = ws + 4352;
    float* invw = ws + 8448;
    float* push = ws + 8704;

    __shared__ float muT[DD * SEGS];
    int t = threadIdx.x;  // 256 threads == one per segment
    float cnt = seg_cnt[t];
    float ic  = (cnt > 0.0f) ? 1.0f / cnt : 0.0f;
    #pragma unroll
    for (int d = 0; d < DD; ++d) {
        float m = seg_sum[t * DD + d] * ic;
        mus[t * DD + d]  = m;
        muT[d * SEGS + t] = m;
    }
    invw[t] = (cnt > 0.0f) ? 1.0f / ((float)MM * cnt) : 0.0f;
    __syncthreads();

    int b = t >> 5, m1 = t & 31;
    float acc = 0.0f;
    for (int m2 = 0; m2 < MM; ++m2) {
        float pd = 0.0f;
        #pragma unroll
        for (int d = 0; d < DD; ++d)
            pd += fabsf(muT[d * SEGS + b * MM + m1] - muT[d * SEGS + b * MM + m2]);
        float h = 2.0f * DELTA_D - pd;
        if (m2 != m1 && h > 0.0f) acc += h * h;
    }
    float tot = block_reduce_sum(acc);
    if (t == 0) push[0] = tot / (float)(MM * (MM - 1));
}

__global__ void __launch_bounds__(NTHR, 4)
k_pull(const float4* __restrict__ o4,
       const int* __restrict__ labels,
       const int* __restrict__ sub,
       const float* __restrict__ mus,
       const float* __restrict__ invw,
       float* __restrict__ pull_part,
       int n) {
    __shared__ float muT[DD * SEGS];  // transposed: conflict-free per-d reads
    __shared__ float siw[SEGS];
    for (int i = threadIdx.x; i < DD * SEGS; i += NTHR) {
        int s = i & (SEGS - 1);
        int d = i >> 8;
        muT[d * SEGS + s] = mus[s * DD + d];
    }
    for (int i = threadIdx.x; i < SEGS; i += NTHR) siw[i] = invw[i];
    __syncthreads();

    float acc = 0.0f;
    const int stride = gridDim.x * NTHR;
    #pragma unroll 2
    for (int p = blockIdx.x * NTHR + threadIdx.x; p < n; p += stride) {
        int lb = labels[p];
        int sb = sub[p];
        float4 a = o4[4 * p + 0];
        float4 b = o4[4 * p + 1];
        float4 c = o4[4 * p + 2];
        float4 e = o4[4 * p + 3];
        float ss = a.x*a.x + a.y*a.y + a.z*a.z + a.w*a.w
                 + b.x*b.x + b.y*b.y + b.z*b.z + b.w*b.w
                 + c.x*c.x + c.y*c.y + c.z*c.z + c.w*c.w
                 + e.x*e.x + e.y*e.y + e.z*e.z + e.w*e.w;
        float rn = 1.0f / (sqrtf(ss) + NEPS);
        int seg = sb * MM + lb;
        float dist;
        dist  = fabsf(muT[ 0*SEGS + seg] - a.x * rn);
        dist += fabsf(muT[ 1*SEGS + seg] - a.y * rn);
        dist += fabsf(muT[ 2*SEGS + seg] - a.z * rn);
        dist += fabsf(muT[ 3*SEGS + seg] - a.w * rn);
        dist += fabsf(muT[ 4*SEGS + seg] - b.x * rn);
        dist += fabsf(muT[ 5*SEGS + seg] - b.y * rn);
        dist += fabsf(muT[ 6*SEGS + seg] - b.z * rn);
        dist += fabsf(muT[ 7*SEGS + seg] - b.w * rn);
        dist += fabsf(muT[ 8*SEGS + seg] - c.x * rn);
        dist += fabsf(muT[ 9*SEGS + seg] - c.y * rn);
        dist += fabsf(muT[10*SEGS + seg] - c.z * rn);
        dist += fabsf(muT[11*SEGS + seg] - c.w * rn);
        dist += fabsf(muT[12*SEGS + seg] - e.x * rn);
        dist += fabsf(muT[13*SEGS + seg] - e.y * rn);
        dist += fabsf(muT[14*SEGS + seg] - e.z * rn);
        dist += fabsf(muT[15*SEGS + seg] - e.w * rn);
        float h = dist - DELTA_V;
        if (h > 0.0f) acc = fmaf(h * h, siw[seg], acc);
    }
    float tot = block_reduce_sum(acc);
    if (threadIdx.x == 0) pull_part[blockIdx.x] = tot;
}

__global__ void k_final(const float* __restrict__ ws, float* __restrict__ out) {
    const float* push      = ws + 8704;
    const float* pull_part = ws + 8705;
    int t = threadIdx.x;
    float v = pull_part[t] + pull_part[t + 256];
    float tot = block_reduce_sum(v);
    if (t == 0) out[0] = (tot + push[0]) * (1.0f / (float)BBATCH);
}

extern "C" void kernel_launch(void* const* d_in, const int* in_sizes, int n_in,
                              void* d_out, int out_size, void* d_ws, size_t ws_size,
                              hipStream_t stream) {
    const float* outputs = (const float*)d_in[0];
    const int* labels    = (const int*)d_in[1];
    const int* sub       = (const int*)d_in[2];
    int n = in_sizes[0] / DD;

    float* ws       = (float*)d_ws;
    float* seg_sum  = ws;
    float* seg_cnt  = ws + 4096;
    float* mus      = ws + 4352;
    float* invw     = ws + 8448;
    float* pull_part= ws + 8705;

    hipMemsetAsync(d_ws, 0, WS_ZERO_FLOATS * sizeof(float), stream);

    k_segsum<<<NBLK, NTHR, 0, stream>>>((const float4*)outputs, labels, sub,
                                        seg_sum, seg_cnt, n);
    k_finalize_push<<<1, NTHR, 0, stream>>>(ws);
    k_pull<<<NBLK, NTHR, 0, stream>>>((const float4*)outputs, labels, sub,
                                      mus, invw, pull_part, n);
    k_final<<<1, NTHR, 0, stream>>>(ws, (float*)d_out);
}